// Round 6
// baseline (96.724 us; speedup 1.0000x reference)
//
#include <hip/hip_runtime.h>
#include <math.h>

#define NROWS 65536
#define NCLS  1000
#define NV4   250          // float4 chunks per row (1000/4)
#define BLOCKS 2048
#define WPB    4           // waves per block
#define NWAVES (BLOCKS * WPB)   // 8192 waves; each wave owns 8 CONTIGUOUS rows

__device__ __forceinline__ float exp4(const float4 v) {
  return (__expf(v.x) + __expf(v.y)) + (__expf(v.z) + __expf(v.w));
}

__device__ __forceinline__ float pick(const float4 v0, const float4 v1,
                                      const float4 v2, const float4 v3,
                                      const int kq, const int comp) {
  const float4 vt = (kq == 0) ? v0 : (kq == 1) ? v1 : (kq == 2) ? v2 : v3;
  return (comp == 0) ? vt.x : (comp == 1) ? vt.y : (comp == 2) ? vt.z : vt.w;
}

// Full per-pair computation: softmax-sum reduce, target extract, focal term.
__device__ __forceinline__ float pair_term(
    const float4 a0, const float4 a1, const float4 a2, const float4 a3,
    const float4 b0, const float4 b1, const float4 b2, const float4 b3,
    const int tA, const int tB,
    const float gA, const float aA, const float gB, const float aB,
    const float w3) {
  float sA = (exp4(a0) + exp4(a1)) + (exp4(a2) + w3 * exp4(a3));
  float sB = (exp4(b0) + exp4(b1)) + (exp4(b2) + w3 * exp4(b3));
#pragma unroll
  for (int o = 32; o > 0; o >>= 1) {
    sA += __shfl_xor(sA, o);
    sB += __shfl_xor(sB, o);
  }
  const float xtA = __shfl(pick(a0, a1, a2, a3, tA >> 8, tA & 3), (tA >> 2) & 63);
  const float xtB = __shfl(pick(b0, b1, b2, b3, tB >> 8, tB & 3), (tB >> 2) & 63);

  const float ceA = __logf(sA) - xtA;
  const float ptA = __expf(-ceA);
  const float ceB = __logf(sB) - xtB;
  const float ptB = __expf(-ceB);
  return aA * __powf(1.0f - ptA, gA) * ceA +
         aB * __powf(1.0f - ptB, gB) * ceB;
}

__global__ __launch_bounds__(256, 6) void focal_stage1(
    const float* __restrict__ inp,
    const int*   __restrict__ tgt,
    const float* __restrict__ gamma_t,
    const float* __restrict__ alpha_t,
    float* __restrict__ partial) {

  __shared__ float wsum[WPB];
  const int lane = threadIdx.x & 63;
  const int wid  = threadIdx.x >> 6;
  const int gw   = blockIdx.x * WPB + wid;

  // tail chunk: lanes 58..63 clamp to last float4, mask contribution
  const int   i3  = lane + 192;
  const int   i3c = (i3 < NV4) ? i3 : (NV4 - 1);
  const float w3  = (i3 < NV4) ? 1.0f : 0.0f;

  float acc = 0.0f;

  // Each wave: 8 contiguous rows [8*gw, 8*gw+8), processed as 4 adjacent
  // pairs (r, r+1). One wave = one sequential 32 KB stream.
  const int row0 = gw * 8;

  // ---- prologue: load pair 0
  int rA = row0;
  const float4* pA = reinterpret_cast<const float4*>(inp + (size_t)rA * NCLS);
  const float4* pB = pA + NV4;              // row rA+1 (contiguous)
  int   tA = tgt[rA],      tB = tgt[rA + 1];
  float gA = gamma_t[tA],  aA = alpha_t[tA];
  float gB = gamma_t[tB],  aB = alpha_t[tB];
  float4 a0 = pA[lane], a1 = pA[lane + 64], a2 = pA[lane + 128], a3 = pA[i3c];
  float4 b0 = pB[lane], b1 = pB[lane + 64], b2 = pB[lane + 128], b3 = pB[i3c];

  // ---- 3 pipelined iterations: issue pair j+1's loads, compute pair j
#pragma unroll 1
  for (int j = 0; j < 3; ++j) {
    const int rA2 = rA + 2;
    const float4* qA = reinterpret_cast<const float4*>(inp + (size_t)rA2 * NCLS);
    const float4* qB = qA + NV4;
    const int   ntA = tgt[rA2],     ntB = tgt[rA2 + 1];
    const float4 na0 = qA[lane], na1 = qA[lane + 64];
    const float4 na2 = qA[lane + 128], na3 = qA[i3c];
    const float4 nb0 = qB[lane], nb1 = qB[lane + 64];
    const float4 nb2 = qB[lane + 128], nb3 = qB[i3c];
    const float ngA = gamma_t[ntA], naA = alpha_t[ntA];
    const float ngB = gamma_t[ntB], naB = alpha_t[ntB];

    // compute current pair while next pair's loads are in flight
    acc += pair_term(a0, a1, a2, a3, b0, b1, b2, b3,
                     tA, tB, gA, aA, gB, aB, w3);

    // rotate
    rA = rA2;
    tA = ntA; tB = ntB; gA = ngA; aA = naA; gB = ngB; aB = naB;
    a0 = na0; a1 = na1; a2 = na2; a3 = na3;
    b0 = nb0; b1 = nb1; b2 = nb2; b3 = nb3;
  }

  // ---- epilogue: final pair
  acc += pair_term(a0, a1, a2, a3, b0, b1, b2, b3,
                   tA, tB, gA, aA, gB, aB, w3);

  // acc is identical across the wave
  if (lane == 0) wsum[wid] = acc;
  __syncthreads();
  if (threadIdx.x == 0) {
    partial[blockIdx.x] = wsum[0] + wsum[1] + wsum[2] + wsum[3];
  }
}

__global__ __launch_bounds__(1024) void focal_stage2(
    const float* __restrict__ partial, float* __restrict__ out) {
  __shared__ float wsum[16];
  const int lane = threadIdx.x & 63;
  const int wid  = threadIdx.x >> 6;

  float s = partial[threadIdx.x] + partial[threadIdx.x + 1024];
#pragma unroll
  for (int o = 32; o > 0; o >>= 1) s += __shfl_xor(s, o);
  if (lane == 0) wsum[wid] = s;
  __syncthreads();
  if (threadIdx.x == 0) {
    float tot = 0.0f;
#pragma unroll
    for (int w = 0; w < 16; ++w) tot += wsum[w];
    out[0] = tot * (1.0f / (float)NROWS);
  }
}

extern "C" void kernel_launch(void* const* d_in, const int* in_sizes, int n_in,
                              void* d_out, int out_size, void* d_ws, size_t ws_size,
                              hipStream_t stream) {
  const float* inp     = (const float*)d_in[0];
  const int*   tgt     = (const int*)  d_in[1];
  const float* gamma_t = (const float*)d_in[2];
  const float* alpha_t = (const float*)d_in[3];
  float* out     = (float*)d_out;
  float* partial = (float*)d_ws;   // BLOCKS floats of scratch

  focal_stage1<<<BLOCKS, 256, 0, stream>>>(inp, tgt, gamma_t, alpha_t, partial);
  focal_stage2<<<1, 1024, 0, stream>>>(partial, out);
}

// Round 7
// 49.292 us; speedup vs baseline: 1.9622x; 1.9622x over previous
//
#include <hip/hip_runtime.h>
#include <math.h>

#define NROWS 65536
#define NCLS  1000
#define NV4   250          // float4 chunks per row (1000/4)
#define BLOCKS 2048
#define WPB    4           // waves per block
#define NWAVES (BLOCKS * WPB)   // 8192 waves; each wave owns 8 CONTIGUOUS rows

__device__ __forceinline__ float exp4(const float4 v) {
  return (__expf(v.x) + __expf(v.y)) + (__expf(v.z) + __expf(v.w));
}

__device__ __forceinline__ float pick(const float4 v0, const float4 v1,
                                      const float4 v2, const float4 v3,
                                      const int kq, const int comp) {
  const float4 vt = (kq == 0) ? v0 : (kq == 1) ? v1 : (kq == 2) ? v2 : v3;
  return (comp == 0) ? vt.x : (comp == 1) ? vt.y : (comp == 2) ? vt.z : vt.w;
}

// Full per-pair computation: softmax-sum reduce, target extract, focal term.
__device__ __forceinline__ float pair_term(
    const float4 a0, const float4 a1, const float4 a2, const float4 a3,
    const float4 b0, const float4 b1, const float4 b2, const float4 b3,
    const int tA, const int tB,
    const float gA, const float aA, const float gB, const float aB,
    const float w3) {
  float sA = (exp4(a0) + exp4(a1)) + (exp4(a2) + w3 * exp4(a3));
  float sB = (exp4(b0) + exp4(b1)) + (exp4(b2) + w3 * exp4(b3));
#pragma unroll
  for (int o = 32; o > 0; o >>= 1) {
    sA += __shfl_xor(sA, o);
    sB += __shfl_xor(sB, o);
  }
  const float xtA = __shfl(pick(a0, a1, a2, a3, tA >> 8, tA & 3), (tA >> 2) & 63);
  const float xtB = __shfl(pick(b0, b1, b2, b3, tB >> 8, tB & 3), (tB >> 2) & 63);

  const float ceA = __logf(sA) - xtA;
  const float ptA = __expf(-ceA);
  const float ceB = __logf(sB) - xtB;
  const float ptB = __expf(-ceB);
  return aA * __powf(1.0f - ptA, gA) * ceA +
         aB * __powf(1.0f - ptB, gB) * ceB;
}

__global__ __launch_bounds__(256) void focal_stage1(
    const float* __restrict__ inp,
    const int*   __restrict__ tgt,
    const float* __restrict__ gamma_t,
    const float* __restrict__ alpha_t,
    float* __restrict__ partial) {

  __shared__ float wsum[WPB];
  const int lane = threadIdx.x & 63;
  const int wid  = threadIdx.x >> 6;
  const int gw   = blockIdx.x * WPB + wid;

  // tail chunk: lanes 58..63 clamp to last float4, mask contribution
  const int   i3  = lane + 192;
  const int   i3c = (i3 < NV4) ? i3 : (NV4 - 1);
  const float w3  = (i3 < NV4) ? 1.0f : 0.0f;

  float acc = 0.0f;

  // Each wave: 8 contiguous rows [8*gw, 8*gw+8), processed as 4 adjacent
  // pairs (r, r+1). One wave = one sequential 32 KB stream.
  const int row0 = gw * 8;

  // ---- prologue: load pair 0
  int rA = row0;
  const float4* pA = reinterpret_cast<const float4*>(inp + (size_t)rA * NCLS);
  const float4* pB = pA + NV4;              // row rA+1 (contiguous)
  int   tA = tgt[rA],      tB = tgt[rA + 1];
  float gA = gamma_t[tA],  aA = alpha_t[tA];
  float gB = gamma_t[tB],  aB = alpha_t[tB];
  float4 a0 = pA[lane], a1 = pA[lane + 64], a2 = pA[lane + 128], a3 = pA[i3c];
  float4 b0 = pB[lane], b1 = pB[lane + 64], b2 = pB[lane + 128], b3 = pB[i3c];

  // ---- 3 pipelined iterations: issue pair j+1's loads, compute pair j
#pragma unroll 1
  for (int j = 0; j < 3; ++j) {
    const int rA2 = rA + 2;
    const float4* qA = reinterpret_cast<const float4*>(inp + (size_t)rA2 * NCLS);
    const float4* qB = qA + NV4;
    const int   ntA = tgt[rA2],     ntB = tgt[rA2 + 1];
    const float4 na0 = qA[lane], na1 = qA[lane + 64];
    const float4 na2 = qA[lane + 128], na3 = qA[i3c];
    const float4 nb0 = qB[lane], nb1 = qB[lane + 64];
    const float4 nb2 = qB[lane + 128], nb3 = qB[i3c];
    const float ngA = gamma_t[ntA], naA = alpha_t[ntA];
    const float ngB = gamma_t[ntB], naB = alpha_t[ntB];

    // compute current pair while next pair's loads are in flight
    acc += pair_term(a0, a1, a2, a3, b0, b1, b2, b3,
                     tA, tB, gA, aA, gB, aB, w3);

    // rotate
    rA = rA2;
    tA = ntA; tB = ntB; gA = ngA; aA = naA; gB = ngB; aB = naB;
    a0 = na0; a1 = na1; a2 = na2; a3 = na3;
    b0 = nb0; b1 = nb1; b2 = nb2; b3 = nb3;
  }

  // ---- epilogue: final pair
  acc += pair_term(a0, a1, a2, a3, b0, b1, b2, b3,
                   tA, tB, gA, aA, gB, aB, w3);

  // acc is identical across the wave
  if (lane == 0) wsum[wid] = acc;
  __syncthreads();
  if (threadIdx.x == 0) {
    partial[blockIdx.x] = wsum[0] + wsum[1] + wsum[2] + wsum[3];
  }
}

__global__ __launch_bounds__(1024) void focal_stage2(
    const float* __restrict__ partial, float* __restrict__ out) {
  __shared__ float wsum[16];
  const int lane = threadIdx.x & 63;
  const int wid  = threadIdx.x >> 6;

  float s = partial[threadIdx.x] + partial[threadIdx.x + 1024];
#pragma unroll
  for (int o = 32; o > 0; o >>= 1) s += __shfl_xor(s, o);
  if (lane == 0) wsum[wid] = s;
  __syncthreads();
  if (threadIdx.x == 0) {
    float tot = 0.0f;
#pragma unroll
    for (int w = 0; w < 16; ++w) tot += wsum[w];
    out[0] = tot * (1.0f / (float)NROWS);
  }
}

extern "C" void kernel_launch(void* const* d_in, const int* in_sizes, int n_in,
                              void* d_out, int out_size, void* d_ws, size_t ws_size,
                              hipStream_t stream) {
  const float* inp     = (const float*)d_in[0];
  const int*   tgt     = (const int*)  d_in[1];
  const float* gamma_t = (const float*)d_in[2];
  const float* alpha_t = (const float*)d_in[3];
  float* out     = (float*)d_out;
  float* partial = (float*)d_ws;   // BLOCKS floats of scratch

  focal_stage1<<<BLOCKS, 256, 0, stream>>>(inp, tgt, gamma_t, alpha_t, partial);
  focal_stage2<<<1, 1024, 0, stream>>>(partial, out);
}